// Round 10
// baseline (512.457 us; speedup 1.0000x reference)
//
#include <hip/hip_runtime.h>
#include <stdint.h>

#define T_TOK 8192   // B*S
#define HDIM  1024
#define FDIM  4096
#define NEXP  8
#define BT    256    // GEMM tile M=N
#define RCAP  (2*T_TOK + NEXP*256)   // 18432 padded rows
#define LDSB  65536  // bytes per LDS double-buffer half (A 32K + B 32K)

typedef short  short8  __attribute__((ext_vector_type(8)));
typedef unsigned short ushort8 __attribute__((ext_vector_type(8)));
typedef float  f32x4   __attribute__((ext_vector_type(4)));

#define MFMA __builtin_amdgcn_mfma_f32_16x16x32_bf16

__device__ __forceinline__ unsigned short f2bf(float f) {
  unsigned u = __float_as_uint(f);
  u += 0x7fffu + ((u >> 16) & 1u);   // RNE
  return (unsigned short)(u >> 16);
}
__device__ __forceinline__ float bf2f(unsigned short u) {
  return __uint_as_float((unsigned)u << 16);
}

__device__ __forceinline__ void gload16(const void* g, void* l) {
  __builtin_amdgcn_global_load_lds(
      (const __attribute__((address_space(1))) void*)g,
      (__attribute__((address_space(3))) void*)l, 16, 0, 0);
}

// ---------------- weight transpose+convert: in [K][N] f32 -> out [N][K] bf16 ----------------
__global__ __launch_bounds__(256) void k_transp_cvt(const float* __restrict__ in,
                                                    unsigned short* __restrict__ out,
                                                    int K, int N) {
  __shared__ unsigned short s[64][72];
  const float* ine = in + (size_t)blockIdx.z * K * N;
  unsigned short* oute = out + (size_t)blockIdx.z * K * N;
  int k0 = blockIdx.y * 64, n0 = blockIdx.x * 64;
  int t = threadIdx.x;
  int kr = t >> 4, nc = (t & 15) * 4;
#pragma unroll
  for (int it = 0; it < 4; ++it) {
    int k = it * 16 + kr;
    float4 v = *(const float4*)(ine + (size_t)(k0 + k) * N + n0 + nc);
    ushort4 u = make_ushort4(f2bf(v.x), f2bf(v.y), f2bf(v.z), f2bf(v.w));
    *(ushort4*)(&s[k][nc]) = u;
  }
  __syncthreads();
  int nr = t >> 3, kc = (t & 7) * 8;
#pragma unroll
  for (int v = 0; v < 2; ++v) {
    int n = v * 32 + nr;
    ushort8 o;
#pragma unroll
    for (int j = 0; j < 8; ++j) o[j] = s[kc + j][n];
    *(ushort8*)(oute + (size_t)(n0 + n) * K + k0 + kc) = o;
  }
}

// ---------------- gating (+ fused x -> bf16 convert) ----------------
__global__ void k_gate(const float* __restrict__ x, const float* __restrict__ gw,
                       unsigned short* __restrict__ xb,
                       int2* __restrict__ eidx, float2* __restrict__ ewt) {
  int tid = threadIdx.x;
  int lane = tid & 63;
  int t = blockIdx.x * 4 + (tid >> 6);
  const float* xr = x + (size_t)t * HDIM;
  unsigned short* xbr = xb + (size_t)t * HDIM;
  float acc[NEXP];
#pragma unroll
  for (int e = 0; e < NEXP; e++) acc[e] = 0.f;
#pragma unroll
  for (int i = 0; i < HDIM / 64; i++) {
    float xv = xr[i * 64 + lane];
    xbr[i * 64 + lane] = f2bf(xv);
#pragma unroll
    for (int e = 0; e < NEXP; e++) acc[e] += xv * gw[e * HDIM + i * 64 + lane];
  }
#pragma unroll
  for (int e = 0; e < NEXP; e++) {
    acc[e] += __shfl_xor(acc[e], 32);
    acc[e] += __shfl_xor(acc[e], 16);
    acc[e] += __shfl_xor(acc[e], 8);
    acc[e] += __shfl_xor(acc[e], 4);
    acc[e] += __shfl_xor(acc[e], 2);
    acc[e] += __shfl_xor(acc[e], 1);
  }
  float m = acc[0];
#pragma unroll
  for (int e = 1; e < NEXP; e++) m = fmaxf(m, acc[e]);
  float p[NEXP]; float s = 0.f;
#pragma unroll
  for (int e = 0; e < NEXP; e++) { p[e] = expf(acc[e] - m); s += p[e]; }
  float inv = 1.f / s;
#pragma unroll
  for (int e = 0; e < NEXP; e++) p[e] *= inv;
  int b0 = 0; float v0 = p[0];
#pragma unroll
  for (int e = 1; e < NEXP; e++) if (p[e] > v0) { v0 = p[e]; b0 = e; }
  int b1i = (b0 == 0) ? 1 : 0; float v1 = p[b1i];
#pragma unroll
  for (int e = 0; e < NEXP; e++) if (e != b0 && p[e] > v1) { v1 = p[e]; b1i = e; }
  if (lane == 0) { eidx[t] = make_int2(b0, b1i); ewt[t] = make_float2(v0, v1); }
}

// ---------------- deterministic per-expert compaction ----------------
__global__ void k_compact(const int2* __restrict__ eidx,
                          int* __restrict__ list_tok, int* __restrict__ counts) {
  int e = blockIdx.x;
  int tid = threadIdx.x, lane = tid & 63, wid = tid >> 6;
  __shared__ int sbase;
  __shared__ int wcnt[4];
  if (tid == 0) sbase = 0;
  __syncthreads();
  for (int c = 0; c < T_TOK; c += 256) {
    int t = c + tid;
    int2 ei = eidx[t];
    bool sel = (ei.x == e) || (ei.y == e);
    unsigned long long b = __ballot(sel);
    if (lane == 0) wcnt[wid] = __popcll(b);
    __syncthreads();
    int pre = sbase;
    for (int w = 0; w < wid; w++) pre += wcnt[w];
    int pos = pre + __popcll(b & ((1ull << lane) - 1ull));
    if (sel) list_tok[e * T_TOK + pos] = t;
    __syncthreads();
    if (tid == 0) sbase += wcnt[0] + wcnt[1] + wcnt[2] + wcnt[3];
    __syncthreads();
  }
  if (tid == 0) counts[e] = sbase;
}

__global__ void k_offsets(const int* __restrict__ counts, int* __restrict__ off_pad) {
  if (threadIdx.x == 0) {
    int o = 0;
    off_pad[0] = 0;
    for (int e = 0; e < NEXP; e++) {
      o += ((counts[e] + BT - 1) / BT) * BT;
      off_pad[e + 1] = o;
    }
  }
}

// ---------------- invert token->padded-slot map (deterministic) ----------------
__global__ void k_invert(const int* __restrict__ list_tok, const int* __restrict__ counts,
                         const int* __restrict__ off_pad, const int2* __restrict__ eidx,
                         int2* __restrict__ tok2slot) {
  int e = blockIdx.y;
  int p = blockIdx.x * 256 + threadIdx.x;
  if (p < counts[e]) {
    int t = list_tok[e * T_TOK + p];
    int slot = off_pad[e] + p;
    if (eidx[t].x == e) tok2slot[t].x = slot;
    else                tok2slot[t].y = slot;
  }
}

// ======== shared GEMM machinery (macros reference kernel-local names) ========
// LDS map per buffer (v&1): A0 @0, A1 @16K, B0 @32K, B1 @48K. 16KB units of 128 rows x 128B.
// LDS read addresses hoisted: per-lane base (aoff*/boff*) + compile-time imm (m*2048).
#define STAGE_A(u_, v_) { \
    char* lb_ = smem + (((v_)&1) ? LDSB : 0) + (u_)*16384; \
    gload16(gA[u_][0] + (size_t)(v_)*128, lb_ + dst0); \
    gload16(gA[u_][1] + (size_t)(v_)*128, lb_ + dst1); }
#define STAGE_B(u_, v_) { \
    char* lb_ = smem + (((v_)&1) ? LDSB : 0) + 32768 + (u_)*16384; \
    gload16(gB[u_][0] + (size_t)(v_)*128, lb_ + dst0); \
    gload16(gB[u_][1] + (size_t)(v_)*128, lb_ + dst1); }

// Merged phase: 8 A-frag reads + 32 MFMA per barrier region (2 phases per K-tile).
// MFMA order: k-half sweep of 16 distinct accumulators (dep distance 16).
#define PHASE2(M0_, M1_, M2_, M3_, STAGE_STMT, TAIL_STMT) { \
    short8 a0l = *(const short8*)(pA0 + (M0_)*2048), a0h = *(const short8*)(pA1 + (M0_)*2048); \
    short8 a1l = *(const short8*)(pA0 + (M1_)*2048), a1h = *(const short8*)(pA1 + (M1_)*2048); \
    short8 a2l = *(const short8*)(pA0 + (M2_)*2048), a2h = *(const short8*)(pA1 + (M2_)*2048); \
    short8 a3l = *(const short8*)(pA0 + (M3_)*2048), a3h = *(const short8*)(pA1 + (M3_)*2048); \
    STAGE_STMT; \
    __builtin_amdgcn_s_barrier(); \
    asm volatile("s_waitcnt lgkmcnt(0)" ::: "memory"); \
    __builtin_amdgcn_sched_barrier(0); \
    __builtin_amdgcn_s_setprio(1); \
    acc[M0_][0] = MFMA(a0l, b00, acc[M0_][0], 0,0,0); \
    acc[M0_][1] = MFMA(a0l, b10, acc[M0_][1], 0,0,0); \
    acc[M0_][2] = MFMA(a0l, b20, acc[M0_][2], 0,0,0); \
    acc[M0_][3] = MFMA(a0l, b30, acc[M0_][3], 0,0,0); \
    acc[M1_][0] = MFMA(a1l, b00, acc[M1_][0], 0,0,0); \
    acc[M1_][1] = MFMA(a1l, b10, acc[M1_][1], 0,0,0); \
    acc[M1_][2] = MFMA(a1l, b20, acc[M1_][2], 0,0,0); \
    acc[M1_][3] = MFMA(a1l, b30, acc[M1_][3], 0,0,0); \
    acc[M2_][0] = MFMA(a2l, b00, acc[M2_][0], 0,0,0); \
    acc[M2_][1] = MFMA(a2l, b10, acc[M2_][1], 0,0,0); \
    acc[M2_][2] = MFMA(a2l, b20, acc[M2_][2], 0,0,0); \
    acc[M2_][3] = MFMA(a2l, b30, acc[M2_][3], 0,0,0); \
    acc[M3_][0] = MFMA(a3l, b00, acc[M3_][0], 0,0,0); \
    acc[M3_][1] = MFMA(a3l, b10, acc[M3_][1], 0,0,0); \
    acc[M3_][2] = MFMA(a3l, b20, acc[M3_][2], 0,0,0); \
    acc[M3_][3] = MFMA(a3l, b30, acc[M3_][3], 0,0,0); \
    acc[M0_][0] = MFMA(a0h, b01, acc[M0_][0], 0,0,0); \
    acc[M0_][1] = MFMA(a0h, b11, acc[M0_][1], 0,0,0); \
    acc[M0_][2] = MFMA(a0h, b21, acc[M0_][2], 0,0,0); \
    acc[M0_][3] = MFMA(a0h, b31, acc[M0_][3], 0,0,0); \
    acc[M1_][0] = MFMA(a1h, b01, acc[M1_][0], 0,0,0); \
    acc[M1_][1] = MFMA(a1h, b11, acc[M1_][1], 0,0,0); \
    acc[M1_][2] = MFMA(a1h, b21, acc[M1_][2], 0,0,0); \
    acc[M1_][3] = MFMA(a1h, b31, acc[M1_][3], 0,0,0); \
    acc[M2_][0] = MFMA(a2h, b01, acc[M2_][0], 0,0,0); \
    acc[M2_][1] = MFMA(a2h, b11, acc[M2_][1], 0,0,0); \
    acc[M2_][2] = MFMA(a2h, b21, acc[M2_][2], 0,0,0); \
    acc[M2_][3] = MFMA(a2h, b31, acc[M2_][3], 0,0,0); \
    acc[M3_][0] = MFMA(a3h, b01, acc[M3_][0], 0,0,0); \
    acc[M3_][1] = MFMA(a3h, b11, acc[M3_][1], 0,0,0); \
    acc[M3_][2] = MFMA(a3h, b21, acc[M3_][2], 0,0,0); \
    acc[M3_][3] = MFMA(a3h, b31, acc[M3_][3], 0,0,0); \
    __builtin_amdgcn_s_setprio(0); \
    TAIL_STMT; \
    __builtin_amdgcn_s_barrier(); }

#define READ_B4 \
    short8 b00 = *(const short8*)(pB0),        b01 = *(const short8*)(pB1); \
    short8 b10 = *(const short8*)(pB0 + 2048), b11 = *(const short8*)(pB1 + 2048); \
    short8 b20 = *(const short8*)(pB0 + 4096), b21 = *(const short8*)(pB1 + 4096); \
    short8 b30 = *(const short8*)(pB0 + 6144), b31 = *(const short8*)(pB1 + 6144);

#define GEMM_TILE_LOOP(NT) \
  STAGE_A(0,0); STAGE_A(1,0); STAGE_B(0,0); STAGE_B(1,0); STAGE_B(0,1); STAGE_B(1,1); \
  asm volatile("s_waitcnt vmcnt(4)" ::: "memory"); \
  __builtin_amdgcn_s_barrier(); \
  for (int v = 0; v < (NT); ++v) { \
    const char* bufb = smem + ((v&1) ? LDSB : 0); \
    const char* pA0 = bufb + wm * 16384 + aoff0; \
    const char* pA1 = bufb + wm * 16384 + aoff1; \
    const char* pB0 = bufb + 32768 + (wn >> 1) * 16384 + boff0; \
    const char* pB1 = bufb + 32768 + (wn >> 1) * 16384 + boff1; \
    READ_B4; \
    PHASE2(0, 1, 2, 3, { if (v+1 < (NT)) { STAGE_A(0, v+1); STAGE_A(1, v+1); } }, {}); \
    PHASE2(4, 5, 6, 7, { if (v+2 < (NT)) { STAGE_B(0, v+2); STAGE_B(1, v+2); } }, { \
      if (v+2 < (NT))      { asm volatile("s_waitcnt vmcnt(4)" ::: "memory"); } \
      else if (v+1 < (NT)) { asm volatile("s_waitcnt vmcnt(0)" ::: "memory"); } }); \
  }

// ---------------- GEMM1: h = silu(gather(x) @ w1[e] + b1[e]), 256x256 tile ----------------
__global__ __launch_bounds__(512, 2) void k_gemm1(
    const unsigned short* __restrict__ xb, const unsigned short* __restrict__ w1t,
    const float* __restrict__ b1, const int* __restrict__ list_tok,
    const int* __restrict__ counts, const int* __restrict__ off_pad,
    unsigned short* __restrict__ h) {
  extern __shared__ char smem[];
  // m-major-within-XCD decode: 1152 blocks = 8 xcd * 144; 16 n-blocks share each m-block.
  int wl = (blockIdx.x & 7) * 144 + (blockIdx.x >> 3);
  int r0 = (wl >> 4) * BT;
  int n0 = (wl & 15) * BT;
  if (r0 >= off_pad[NEXP]) return;
  int e = 0;
#pragma unroll
  for (int i = 0; i < NEXP; ++i) if (r0 >= off_pad[i + 1]) e = i + 1;
  int base = off_pad[e], cnt = counts[e];

  int t = threadIdx.x, l = t & 63, w = t >> 6;
  int wm = w >> 2, wn = w & 3;
  int lr = l & 15, g16 = (l >> 4) * 16;
  int swz = (lr & 7) << 4;
  int aoff0 = lr * 128 + (g16 ^ swz);
  int aoff1 = lr * 128 + ((64 + g16) ^ swz);
  int boff0 = (wn & 1) * 8192 + aoff0;
  int boff1 = (wn & 1) * 8192 + aoff1;

  int dst0 = t * 16, dst1 = t * 16 + 8192;
  int srow = t >> 3;
  int skb = (((t & 7) ^ ((t >> 3) & 7)) << 4);   // pre-swizzled source k-slot
  const char* gA[2][2];
  const char* gB[2][2];
#pragma unroll
  for (int u = 0; u < 2; ++u)
#pragma unroll
    for (int j = 0; j < 2; ++j) {
      int row = u * 128 + srow + 64 * j;
      int se = r0 - base + row;
      int tok = (se < cnt) ? list_tok[e * T_TOK + se] : 0;
      gA[u][j] = (const char*)(xb + (size_t)tok * HDIM) + skb;
      gB[u][j] = (const char*)(w1t + (size_t)e * FDIM * HDIM + (size_t)(n0 + row) * HDIM) + skb;
    }

  f32x4 acc[8][4];
#pragma unroll
  for (int m = 0; m < 8; ++m)
#pragma unroll
    for (int n = 0; n < 4; ++n) acc[m][n] = (f32x4){0.f, 0.f, 0.f, 0.f};

  GEMM_TILE_LOOP(HDIM / 64);

  // epilogue: bias+silu -> bf16 tile in LDS (col-XOR-swizzled), coalesced 16B stores
  const float* b1e = b1 + (size_t)e * FDIM + n0;
  unsigned short* Cs = (unsigned short*)smem;
  int lh = l >> 4, lh4 = lh * 4;
  int cswz = lh << 4;
#pragma unroll
  for (int n = 0; n < 4; ++n) {
    int col = wn * 64 + n * 16 + lr;
    int colX = col ^ cswz;
    float bv = b1e[col];
#pragma unroll
    for (int m = 0; m < 8; ++m) {
      int row = wm * 128 + m * 16 + lh4;
#pragma unroll
      for (int i = 0; i < 4; ++i) {
        float vv = acc[m][n][i] + bv;
        float sg = __builtin_amdgcn_rcpf(1.f + __expf(-vv));
        Cs[(size_t)(row + i) * BT + colX] = f2bf(vv * sg);
      }
    }
  }
  __syncthreads();
#pragma unroll
  for (int s = 0; s < 16; ++s) {
    int lin = s * 512 + t;
    int row = lin >> 5, c8 = (lin & 31) * 8;
    int c8X = c8 ^ (((row >> 2) & 3) << 4);
    *(ushort8*)(h + (size_t)(r0 + row) * FDIM + n0 + c8) = *(const ushort8*)(Cs + (size_t)row * BT + c8X);
  }
}

// ---------------- GEMM2 (K-split 2): ypart{A,B}[slot][hcol] partials, no atomics ----------------
__global__ __launch_bounds__(512, 2) void k_gemm2(
    const unsigned short* __restrict__ h, const unsigned short* __restrict__ w2t,
    const float* __restrict__ b2, const int* __restrict__ off_pad,
    unsigned short* __restrict__ ypartA, unsigned short* __restrict__ ypartB) {
  extern __shared__ char smem[];
  // m-major-within-XCD decode: 576 blocks = 8 xcd * 72; 8 (n,z) share each m-block.
  int wl = (blockIdx.x & 7) * 72 + (blockIdx.x >> 3);
  int mB = wl >> 3, rem = wl & 7;
  int r0 = mB * BT;                 // slot block
  int n0 = (rem >> 1) * BT;         // hcol block
  int z  = rem & 1;                 // K half: f in [z*2048, z*2048+2048)
  if (r0 >= off_pad[NEXP]) return;
  int e = 0;
#pragma unroll
  for (int i = 0; i < NEXP; ++i) if (r0 >= off_pad[i + 1]) e = i + 1;

  int t = threadIdx.x, l = t & 63, w = t >> 6;
  int wm = w >> 2, wn = w & 3;
  int lr = l & 15, g16 = (l >> 4) * 16;
  int swz = (lr & 7) << 4;
  int aoff0 = lr * 128 + (g16 ^ swz);
  int aoff1 = lr * 128 + ((64 + g16) ^ swz);
  int boff0 = (wn & 1) * 8192 + aoff0;
  int boff1 = (wn & 1) * 8192 + aoff1;

  int dst0 = t * 16, dst1 = t * 16 + 8192;
  int srow = t >> 3;
  int skb = (((t & 7) ^ ((t >> 3) & 7)) << 4);
  const char* gA[2][2];
  const char* gB[2][2];
#pragma unroll
  for (int u = 0; u < 2; ++u)
#pragma unroll
    for (int j = 0; j < 2; ++j) {
      int row = u * 128 + srow + 64 * j;
      gA[u][j] = (const char*)(h + (size_t)(r0 + row) * FDIM + (size_t)z * 2048) + skb;
      gB[u][j] = (const char*)(w2t + (size_t)e * HDIM * FDIM + (size_t)(n0 + row) * FDIM + (size_t)z * 2048) + skb;
    }

  f32x4 acc[8][4];
#pragma unroll
  for (int m = 0; m < 8; ++m)
#pragma unroll
    for (int n = 0; n < 4; ++n) acc[m][n] = (f32x4){0.f, 0.f, 0.f, 0.f};

  GEMM_TILE_LOOP(2048 / 64);

  // epilogue: (+b2 on z==0) -> bf16 tile in LDS (col-XOR-swizzled), coalesced stores
  const float* b2e = b2 + (size_t)e * HDIM + n0;
  unsigned short* yp = z ? ypartB : ypartA;
  unsigned short* Cs = (unsigned short*)smem;
  int lh = l >> 4, lh4 = lh * 4;
  int cswz = lh << 4;
#pragma unroll
  for (int n = 0; n < 4; ++n) {
    int col = wn * 64 + n * 16 + lr;
    int colX = col ^ cswz;
    float bv = (z == 0) ? b2e[col] : 0.f;
#pragma unroll
    for (int m = 0; m < 8; ++m) {
      int row = wm * 128 + m * 16 + lh4;
#pragma unroll
      for (int i = 0; i < 4; ++i)
        Cs[(size_t)(row + i) * BT + colX] = f2bf(acc[m][n][i] + bv);
    }
  }
  __syncthreads();
#pragma unroll
  for (int s = 0; s < 16; ++s) {
    int lin = s * 512 + t;
    int row = lin >> 5, c8 = (lin & 31) * 8;
    int c8X = c8 ^ (((row >> 2) & 3) << 4);
    *(ushort8*)(yp + (size_t)(r0 + row) * HDIM + n0 + c8) = *(const ushort8*)(Cs + (size_t)row * BT + c8X);
  }
}

// ---------------- final combine: out[t] = w0*(yA+yB)[s0] + w1*(yA+yB)[s1] ----------------
__global__ void k_reduce(const unsigned short* __restrict__ ypartA,
                         const unsigned short* __restrict__ ypartB,
                         const int2* __restrict__ tok2slot, const float2* __restrict__ ewt,
                         float* __restrict__ out) {
  int idx = blockIdx.x * 256 + threadIdx.x;   // 8 cols per thread
  int t = idx >> 7;
  int c8 = (idx & 127) * 8;
  int2 s = tok2slot[t];
  float2 wv = ewt[t];
  ushort8 a0 = *(const ushort8*)(ypartA + (size_t)s.x * HDIM + c8);
  ushort8 a1 = *(const ushort8*)(ypartB + (size_t)s.x * HDIM + c8);
  ushort8 b0 = *(const ushort8*)(ypartA + (size_t)s.y * HDIM + c8);
  ushort8 b1 = *(const ushort8*)(ypartB + (size_t)s.y * HDIM + c8);
  float o[8];
#pragma unroll
  for (int j = 0; j < 8; ++j)
    o[j] = wv.x * (bf2f((unsigned short)a0[j]) + bf2f((unsigned short)a1[j]))
         + wv.y * (bf2f((unsigned short)b0[j]) + bf2f((unsigned short)b1[j]));
  float* op = out + (size_t)t * HDIM + c8;
  *(float4*)op = make_float4(o[0], o[1], o[2], o[3]);
  *(float4*)(op + 4) = make_float4(o[4], o[5], o[6], o[7]);
}

extern "C" void kernel_launch(void* const* d_in, const int* in_sizes, int n_in,
                              void* d_out, int out_size, void* d_ws, size_t ws_size,
                              hipStream_t stream) {
  const float* x  = (const float*)d_in[0];
  const float* gw = (const float*)d_in[1];
  const float* w1 = (const float*)d_in[2];
  const float* b1 = (const float*)d_in[3];
  const float* w2 = (const float*)d_in[4];
  const float* b2 = (const float*)d_in[5];
  float* out = (float*)d_out;

  char* ws = (char*)d_ws;
  size_t off = 0;
  unsigned short* xb = (unsigned short*)(ws + off); off += (size_t)T_TOK * HDIM * 2;
  int2*   eidx = (int2*)(ws + off);   off += (size_t)T_TOK * 8;
  float2* ewt  = (float2*)(ws + off); off += (size_t)T_TOK * 8;
  int2* tok2slot = (int2*)(ws + off); off += (size_t)T_TOK * 8;
  int*  list_tok = (int*)(ws + off);  off += (size_t)NEXP * T_TOK * 4;
  int* counts  = (int*)(ws + off); off += 64;
  int* off_pad = (int*)(ws + off); off += 64;
  off = (off + 255) & ~(size_t)255;
  unsigned short* h      = (unsigned short*)(ws + off); off += (size_t)RCAP * FDIM * 2;
  unsigned short* wT     = (unsigned short*)(ws + off); off += (size_t)NEXP * HDIM * FDIM * 2;
  unsigned short* ypartA = (unsigned short*)(ws + off); off += (size_t)RCAP * HDIM * 2;
  unsigned short* ypartB = (unsigned short*)(ws + off); off += (size_t)RCAP * HDIM * 2;
  if (ws_size < off) return;  // workspace too small -> fail loudly

  hipFuncSetAttribute((const void*)k_gemm1, hipFuncAttributeMaxDynamicSharedMemorySize, 131072);
  hipFuncSetAttribute((const void*)k_gemm2, hipFuncAttributeMaxDynamicSharedMemorySize, 131072);

  k_gate<<<T_TOK / 4, 256, 0, stream>>>(x, gw, xb, eidx, ewt);
  k_compact<<<NEXP, 256, 0, stream>>>(eidx, list_tok, counts);
  k_offsets<<<1, 64, 0, stream>>>(counts, off_pad);
  k_invert<<<dim3(T_TOK / 256, NEXP), 256, 0, stream>>>(list_tok, counts, off_pad, eidx, tok2slot);
  // w1 [E][H][F] f32 -> wT [E][F][H] bf16
  k_transp_cvt<<<dim3(FDIM / 64, HDIM / 64, NEXP), 256, 0, stream>>>(w1, wT, HDIM, FDIM);
  k_gemm1<<<8 * 144, 512, 131072, stream>>>(xb, wT, b1, list_tok, counts, off_pad, h);
  // w2 [E][F][H] f32 -> wT [E][H][F] bf16 (buffer reuse after GEMM1)
  k_transp_cvt<<<dim3(HDIM / 64, FDIM / 64, NEXP), 256, 0, stream>>>(w2, wT, FDIM, HDIM);
  k_gemm2<<<8 * 72, 512, 131072, stream>>>(h, wT, b2, off_pad, ypartA, ypartB);
  k_reduce<<<T_TOK * (HDIM / 8) / 256, 256, 0, stream>>>(ypartA, ypartB, tok2slot, ewt, out);
}

// Round 11
// 464.324 us; speedup vs baseline: 1.1037x; 1.1037x over previous
//
#include <hip/hip_runtime.h>
#include <stdint.h>

#define T_TOK 8192   // B*S
#define HDIM  1024
#define FDIM  4096
#define NEXP  8
#define BT    256    // GEMM tile M=N
#define RCAP  (2*T_TOK + NEXP*256)   // 18432 padded rows
#define LDSB  65536  // bytes per LDS double-buffer half (A 32K + B 32K)

typedef short  short8  __attribute__((ext_vector_type(8)));
typedef unsigned short ushort8 __attribute__((ext_vector_type(8)));
typedef float  f32x4   __attribute__((ext_vector_type(4)));

#define MFMA __builtin_amdgcn_mfma_f32_16x16x32_bf16

__device__ __forceinline__ unsigned short f2bf(float f) {
  unsigned u = __float_as_uint(f);
  u += 0x7fffu + ((u >> 16) & 1u);   // RNE
  return (unsigned short)(u >> 16);
}
__device__ __forceinline__ float bf2f(unsigned short u) {
  return __uint_as_float((unsigned)u << 16);
}

__device__ __forceinline__ void gload16(const void* g, void* l) {
  __builtin_amdgcn_global_load_lds(
      (const __attribute__((address_space(1))) void*)g,
      (__attribute__((address_space(3))) void*)l, 16, 0, 0);
}

// ---------------- weight transpose+convert: in [K][N] f32 -> out [N][K] bf16 ----------------
__global__ __launch_bounds__(256) void k_transp_cvt(const float* __restrict__ in,
                                                    unsigned short* __restrict__ out,
                                                    int K, int N) {
  __shared__ unsigned short s[64][72];
  const float* ine = in + (size_t)blockIdx.z * K * N;
  unsigned short* oute = out + (size_t)blockIdx.z * K * N;
  int k0 = blockIdx.y * 64, n0 = blockIdx.x * 64;
  int t = threadIdx.x;
  int kr = t >> 4, nc = (t & 15) * 4;
#pragma unroll
  for (int it = 0; it < 4; ++it) {
    int k = it * 16 + kr;
    float4 v = *(const float4*)(ine + (size_t)(k0 + k) * N + n0 + nc);
    ushort4 u = make_ushort4(f2bf(v.x), f2bf(v.y), f2bf(v.z), f2bf(v.w));
    *(ushort4*)(&s[k][nc]) = u;
  }
  __syncthreads();
  int nr = t >> 3, kc = (t & 7) * 8;
#pragma unroll
  for (int v = 0; v < 2; ++v) {
    int n = v * 32 + nr;
    ushort8 o;
#pragma unroll
    for (int j = 0; j < 8; ++j) o[j] = s[kc + j][n];
    *(ushort8*)(oute + (size_t)(n0 + n) * K + k0 + kc) = o;
  }
}

// ---------------- gating (+ fused x -> bf16 convert), float4-vectorized ----------------
__global__ void k_gate(const float* __restrict__ x, const float* __restrict__ gw,
                       unsigned short* __restrict__ xb,
                       int2* __restrict__ eidx, float2* __restrict__ ewt) {
  int tid = threadIdx.x;
  int lane = tid & 63;
  int t = blockIdx.x * 4 + (tid >> 6);
  const float* xr = x + (size_t)t * HDIM;
  unsigned short* xbr = xb + (size_t)t * HDIM;
  float acc[NEXP];
#pragma unroll
  for (int e = 0; e < NEXP; e++) acc[e] = 0.f;
#pragma unroll
  for (int i = 0; i < 4; i++) {
    int idx = i * 256 + lane * 4;
    float4 xv = *(const float4*)(xr + idx);
    *(ushort4*)(xbr + idx) = make_ushort4(f2bf(xv.x), f2bf(xv.y), f2bf(xv.z), f2bf(xv.w));
#pragma unroll
    for (int e = 0; e < NEXP; e++) {
      float4 gv = *(const float4*)(gw + e * HDIM + idx);
      acc[e] += xv.x * gv.x + xv.y * gv.y + xv.z * gv.z + xv.w * gv.w;
    }
  }
#pragma unroll
  for (int e = 0; e < NEXP; e++) {
    acc[e] += __shfl_xor(acc[e], 32);
    acc[e] += __shfl_xor(acc[e], 16);
    acc[e] += __shfl_xor(acc[e], 8);
    acc[e] += __shfl_xor(acc[e], 4);
    acc[e] += __shfl_xor(acc[e], 2);
    acc[e] += __shfl_xor(acc[e], 1);
  }
  float m = acc[0];
#pragma unroll
  for (int e = 1; e < NEXP; e++) m = fmaxf(m, acc[e]);
  float p[NEXP]; float s = 0.f;
#pragma unroll
  for (int e = 0; e < NEXP; e++) { p[e] = expf(acc[e] - m); s += p[e]; }
  float inv = 1.f / s;
#pragma unroll
  for (int e = 0; e < NEXP; e++) p[e] *= inv;
  int b0 = 0; float v0 = p[0];
#pragma unroll
  for (int e = 1; e < NEXP; e++) if (p[e] > v0) { v0 = p[e]; b0 = e; }
  int b1i = (b0 == 0) ? 1 : 0; float v1 = p[b1i];
#pragma unroll
  for (int e = 0; e < NEXP; e++) if (e != b0 && p[e] > v1) { v1 = p[e]; b1i = e; }
  if (lane == 0) { eidx[t] = make_int2(b0, b1i); ewt[t] = make_float2(v0, v1); }
}

// ---------------- deterministic per-expert compaction (1024 threads) ----------------
__global__ __launch_bounds__(1024) void k_compact(const int2* __restrict__ eidx,
                          int* __restrict__ list_tok, int* __restrict__ counts) {
  int e = blockIdx.x;
  int tid = threadIdx.x, lane = tid & 63, wid = tid >> 6;
  __shared__ int sbase;
  __shared__ int wcnt[16];
  if (tid == 0) sbase = 0;
  __syncthreads();
  for (int c = 0; c < T_TOK; c += 1024) {
    int t = c + tid;
    int2 ei = eidx[t];
    bool sel = (ei.x == e) || (ei.y == e);
    unsigned long long b = __ballot(sel);
    if (lane == 0) wcnt[wid] = __popcll(b);
    __syncthreads();
    int pre = sbase;
    for (int w = 0; w < wid; w++) pre += wcnt[w];
    int pos = pre + __popcll(b & ((1ull << lane) - 1ull));
    if (sel) list_tok[e * T_TOK + pos] = t;
    __syncthreads();
    if (tid == 0) {
      int tot = 0;
      for (int w = 0; w < 16; w++) tot += wcnt[w];
      sbase += tot;
    }
    __syncthreads();
  }
  if (tid == 0) counts[e] = sbase;
}

__global__ void k_offsets(const int* __restrict__ counts, int* __restrict__ off_pad) {
  if (threadIdx.x == 0) {
    int o = 0;
    off_pad[0] = 0;
    for (int e = 0; e < NEXP; e++) {
      o += ((counts[e] + BT - 1) / BT) * BT;
      off_pad[e + 1] = o;
    }
  }
}

// ---------------- invert token->padded-slot map (deterministic) ----------------
__global__ void k_invert(const int* __restrict__ list_tok, const int* __restrict__ counts,
                         const int* __restrict__ off_pad, const int2* __restrict__ eidx,
                         int2* __restrict__ tok2slot) {
  int e = blockIdx.y;
  int p = blockIdx.x * 256 + threadIdx.x;
  if (p < counts[e]) {
    int t = list_tok[e * T_TOK + p];
    int slot = off_pad[e] + p;
    if (eidx[t].x == e) tok2slot[t].x = slot;
    else                tok2slot[t].y = slot;
  }
}

// ======== shared GEMM machinery (macros reference kernel-local names) ========
// LDS map per buffer (v&1): A0 @0, A1 @16K, B0 @32K, B1 @48K. 16KB units of 128 rows x 128B.
// LDS read addresses hoisted: per-lane base (aoff*/boff*) + compile-time imm (m*2048).
// No manual lgkm drain: the compiler inserts fine-grained lgkmcnt(N) before each
// MFMA's first use, so reads and MFMA overlap within the region. Compiler-level
// memory fences (empty asm) pin LDS ops to their barrier epoch.
#define CFENCE asm volatile("" ::: "memory")

#define STAGE_A(u_, v_) { \
    char* lb_ = smem + (((v_)&1) ? LDSB : 0) + (u_)*16384; \
    gload16(gA[u_][0] + (size_t)(v_)*128, lb_ + dst0); \
    gload16(gA[u_][1] + (size_t)(v_)*128, lb_ + dst1); }
#define STAGE_B(u_, v_) { \
    char* lb_ = smem + (((v_)&1) ? LDSB : 0) + 32768 + (u_)*16384; \
    gload16(gB[u_][0] + (size_t)(v_)*128, lb_ + dst0); \
    gload16(gB[u_][1] + (size_t)(v_)*128, lb_ + dst1); }

// Merged phase: 8 A-frag reads + 32 MFMA per barrier region (2 phases per K-tile).
#define PHASE2(M0_, M1_, M2_, M3_, STAGE_STMT, TAIL_STMT) { \
    short8 a0l = *(const short8*)(pA0 + (M0_)*2048), a0h = *(const short8*)(pA1 + (M0_)*2048); \
    short8 a1l = *(const short8*)(pA0 + (M1_)*2048), a1h = *(const short8*)(pA1 + (M1_)*2048); \
    short8 a2l = *(const short8*)(pA0 + (M2_)*2048), a2h = *(const short8*)(pA1 + (M2_)*2048); \
    short8 a3l = *(const short8*)(pA0 + (M3_)*2048), a3h = *(const short8*)(pA1 + (M3_)*2048); \
    STAGE_STMT; \
    CFENCE; \
    __builtin_amdgcn_s_barrier(); \
    CFENCE; \
    acc[M0_][0] = MFMA(a0l, b00, acc[M0_][0], 0,0,0); \
    acc[M0_][1] = MFMA(a0l, b10, acc[M0_][1], 0,0,0); \
    acc[M0_][2] = MFMA(a0l, b20, acc[M0_][2], 0,0,0); \
    acc[M0_][3] = MFMA(a0l, b30, acc[M0_][3], 0,0,0); \
    acc[M1_][0] = MFMA(a1l, b00, acc[M1_][0], 0,0,0); \
    acc[M1_][1] = MFMA(a1l, b10, acc[M1_][1], 0,0,0); \
    acc[M1_][2] = MFMA(a1l, b20, acc[M1_][2], 0,0,0); \
    acc[M1_][3] = MFMA(a1l, b30, acc[M1_][3], 0,0,0); \
    acc[M2_][0] = MFMA(a2l, b00, acc[M2_][0], 0,0,0); \
    acc[M2_][1] = MFMA(a2l, b10, acc[M2_][1], 0,0,0); \
    acc[M2_][2] = MFMA(a2l, b20, acc[M2_][2], 0,0,0); \
    acc[M2_][3] = MFMA(a2l, b30, acc[M2_][3], 0,0,0); \
    acc[M3_][0] = MFMA(a3l, b00, acc[M3_][0], 0,0,0); \
    acc[M3_][1] = MFMA(a3l, b10, acc[M3_][1], 0,0,0); \
    acc[M3_][2] = MFMA(a3l, b20, acc[M3_][2], 0,0,0); \
    acc[M3_][3] = MFMA(a3l, b30, acc[M3_][3], 0,0,0); \
    acc[M0_][0] = MFMA(a0h, b01, acc[M0_][0], 0,0,0); \
    acc[M0_][1] = MFMA(a0h, b11, acc[M0_][1], 0,0,0); \
    acc[M0_][2] = MFMA(a0h, b21, acc[M0_][2], 0,0,0); \
    acc[M0_][3] = MFMA(a0h, b31, acc[M0_][3], 0,0,0); \
    acc[M1_][0] = MFMA(a1h, b01, acc[M1_][0], 0,0,0); \
    acc[M1_][1] = MFMA(a1h, b11, acc[M1_][1], 0,0,0); \
    acc[M1_][2] = MFMA(a1h, b21, acc[M1_][2], 0,0,0); \
    acc[M1_][3] = MFMA(a1h, b31, acc[M1_][3], 0,0,0); \
    acc[M2_][0] = MFMA(a2h, b01, acc[M2_][0], 0,0,0); \
    acc[M2_][1] = MFMA(a2h, b11, acc[M2_][1], 0,0,0); \
    acc[M2_][2] = MFMA(a2h, b21, acc[M2_][2], 0,0,0); \
    acc[M2_][3] = MFMA(a2h, b31, acc[M2_][3], 0,0,0); \
    acc[M3_][0] = MFMA(a3h, b01, acc[M3_][0], 0,0,0); \
    acc[M3_][1] = MFMA(a3h, b11, acc[M3_][1], 0,0,0); \
    acc[M3_][2] = MFMA(a3h, b21, acc[M3_][2], 0,0,0); \
    acc[M3_][3] = MFMA(a3h, b31, acc[M3_][3], 0,0,0); \
    TAIL_STMT; \
    CFENCE; \
    __builtin_amdgcn_s_barrier(); \
    CFENCE; }

#define READ_B4 \
    short8 b00 = *(const short8*)(pB0),        b01 = *(const short8*)(pB1); \
    short8 b10 = *(const short8*)(pB0 + 2048), b11 = *(const short8*)(pB1 + 2048); \
    short8 b20 = *(const short8*)(pB0 + 4096), b21 = *(const short8*)(pB1 + 4096); \
    short8 b30 = *(const short8*)(pB0 + 6144), b31 = *(const short8*)(pB1 + 6144);

#define GEMM_TILE_LOOP(NT) \
  STAGE_A(0,0); STAGE_A(1,0); STAGE_B(0,0); STAGE_B(1,0); STAGE_B(0,1); STAGE_B(1,1); \
  asm volatile("s_waitcnt vmcnt(4)" ::: "memory"); \
  __builtin_amdgcn_s_barrier(); \
  CFENCE; \
  for (int v = 0; v < (NT); ++v) { \
    const char* bufb = smem + ((v&1) ? LDSB : 0); \
    const char* pA0 = bufb + wm * 16384 + aoff0; \
    const char* pA1 = bufb + wm * 16384 + aoff1; \
    const char* pB0 = bufb + 32768 + (wn >> 1) * 16384 + boff0; \
    const char* pB1 = bufb + 32768 + (wn >> 1) * 16384 + boff1; \
    READ_B4; \
    PHASE2(0, 1, 2, 3, { if (v+1 < (NT)) { STAGE_A(0, v+1); STAGE_A(1, v+1); } }, {}); \
    PHASE2(4, 5, 6, 7, { if (v+2 < (NT)) { STAGE_B(0, v+2); STAGE_B(1, v+2); } }, { \
      if (v+2 < (NT))      { asm volatile("s_waitcnt vmcnt(4)" ::: "memory"); } \
      else if (v+1 < (NT)) { asm volatile("s_waitcnt vmcnt(0)" ::: "memory"); } }); \
  }

// ---------------- GEMM1: h = silu(gather(x) @ w1[e] + b1[e]), 256x256 tile ----------------
__global__ __launch_bounds__(512, 2) void k_gemm1(
    const unsigned short* __restrict__ xb, const unsigned short* __restrict__ w1t,
    const float* __restrict__ b1, const int* __restrict__ list_tok,
    const int* __restrict__ counts, const int* __restrict__ off_pad,
    unsigned short* __restrict__ h) {
  extern __shared__ char smem[];
  // m-major-within-XCD decode: 1152 blocks = 8 xcd * 144; 16 n-blocks share each m-block.
  int wl = (blockIdx.x & 7) * 144 + (blockIdx.x >> 3);
  int r0 = (wl >> 4) * BT;
  int n0 = (wl & 15) * BT;
  if (r0 >= off_pad[NEXP]) return;
  int e = 0;
#pragma unroll
  for (int i = 0; i < NEXP; ++i) if (r0 >= off_pad[i + 1]) e = i + 1;
  int base = off_pad[e], cnt = counts[e];

  int t = threadIdx.x, l = t & 63, w = t >> 6;
  int wm = w >> 2, wn = w & 3;
  int lr = l & 15, g16 = (l >> 4) * 16;
  int swz = (lr & 7) << 4;
  int aoff0 = lr * 128 + (g16 ^ swz);
  int aoff1 = lr * 128 + ((64 + g16) ^ swz);
  int boff0 = (wn & 1) * 8192 + aoff0;
  int boff1 = (wn & 1) * 8192 + aoff1;

  int dst0 = t * 16, dst1 = t * 16 + 8192;
  int srow = t >> 3;
  int skb = (((t & 7) ^ ((t >> 3) & 7)) << 4);   // pre-swizzled source k-slot
  const char* gA[2][2];
  const char* gB[2][2];
#pragma unroll
  for (int u = 0; u < 2; ++u)
#pragma unroll
    for (int j = 0; j < 2; ++j) {
      int row = u * 128 + srow + 64 * j;
      int se = r0 - base + row;
      int tok = (se < cnt) ? list_tok[e * T_TOK + se] : 0;
      gA[u][j] = (const char*)(xb + (size_t)tok * HDIM) + skb;
      gB[u][j] = (const char*)(w1t + (size_t)e * FDIM * HDIM + (size_t)(n0 + row) * HDIM) + skb;
    }

  f32x4 acc[8][4];
#pragma unroll
  for (int m = 0; m < 8; ++m)
#pragma unroll
    for (int n = 0; n < 4; ++n) acc[m][n] = (f32x4){0.f, 0.f, 0.f, 0.f};

  GEMM_TILE_LOOP(HDIM / 64);

  // epilogue: bias+silu -> bf16 tile in LDS (col-XOR-swizzled), coalesced 16B stores
  const float* b1e = b1 + (size_t)e * FDIM + n0;
  unsigned short* Cs = (unsigned short*)smem;
  int lh = l >> 4, lh4 = lh * 4;
  int cswz = lh << 4;
#pragma unroll
  for (int n = 0; n < 4; ++n) {
    int col = wn * 64 + n * 16 + lr;
    int colX = col ^ cswz;
    float bv = b1e[col];
#pragma unroll
    for (int m = 0; m < 8; ++m) {
      int row = wm * 128 + m * 16 + lh4;
#pragma unroll
      for (int i = 0; i < 4; ++i) {
        float vv = acc[m][n][i] + bv;
        float sg = __builtin_amdgcn_rcpf(1.f + __expf(-vv));
        Cs[(size_t)(row + i) * BT + colX] = f2bf(vv * sg);
      }
    }
  }
  __syncthreads();
#pragma unroll
  for (int s = 0; s < 16; ++s) {
    int lin = s * 512 + t;
    int row = lin >> 5, c8 = (lin & 31) * 8;
    int c8X = c8 ^ (((row >> 2) & 3) << 4);
    *(ushort8*)(h + (size_t)(r0 + row) * FDIM + n0 + c8) = *(const ushort8*)(Cs + (size_t)row * BT + c8X);
  }
}

// ---------------- GEMM2 (K-split 2): ypart{A,B}[slot][hcol] partials, no atomics ----------------
__global__ __launch_bounds__(512, 2) void k_gemm2(
    const unsigned short* __restrict__ h, const unsigned short* __restrict__ w2t,
    const float* __restrict__ b2, const int* __restrict__ off_pad,
    unsigned short* __restrict__ ypartA, unsigned short* __restrict__ ypartB) {
  extern __shared__ char smem[];
  // m-major-within-XCD decode: 576 blocks = 8 xcd * 72; 8 (n,z) share each m-block.
  int wl = (blockIdx.x & 7) * 72 + (blockIdx.x >> 3);
  int mB = wl >> 3, rem = wl & 7;
  int r0 = mB * BT;                 // slot block
  int n0 = (rem >> 1) * BT;         // hcol block
  int z  = rem & 1;                 // K half: f in [z*2048, z*2048+2048)
  if (r0 >= off_pad[NEXP]) return;
  int e = 0;
#pragma unroll
  for (int i = 0; i < NEXP; ++i) if (r0 >= off_pad[i + 1]) e = i + 1;

  int t = threadIdx.x, l = t & 63, w = t >> 6;
  int wm = w >> 2, wn = w & 3;
  int lr = l & 15, g16 = (l >> 4) * 16;
  int swz = (lr & 7) << 4;
  int aoff0 = lr * 128 + (g16 ^ swz);
  int aoff1 = lr * 128 + ((64 + g16) ^ swz);
  int boff0 = (wn & 1) * 8192 + aoff0;
  int boff1 = (wn & 1) * 8192 + aoff1;

  int dst0 = t * 16, dst1 = t * 16 + 8192;
  int srow = t >> 3;
  int skb = (((t & 7) ^ ((t >> 3) & 7)) << 4);
  const char* gA[2][2];
  const char* gB[2][2];
#pragma unroll
  for (int u = 0; u < 2; ++u)
#pragma unroll
    for (int j = 0; j < 2; ++j) {
      int row = u * 128 + srow + 64 * j;
      gA[u][j] = (const char*)(h + (size_t)(r0 + row) * FDIM + (size_t)z * 2048) + skb;
      gB[u][j] = (const char*)(w2t + (size_t)e * HDIM * FDIM + (size_t)(n0 + row) * FDIM + (size_t)z * 2048) + skb;
    }

  f32x4 acc[8][4];
#pragma unroll
  for (int m = 0; m < 8; ++m)
#pragma unroll
    for (int n = 0; n < 4; ++n) acc[m][n] = (f32x4){0.f, 0.f, 0.f, 0.f};

  GEMM_TILE_LOOP(2048 / 64);

  // epilogue: (+b2 on z==0) -> bf16 tile in LDS (col-XOR-swizzled), coalesced stores
  const float* b2e = b2 + (size_t)e * HDIM + n0;
  unsigned short* yp = z ? ypartB : ypartA;
  unsigned short* Cs = (unsigned short*)smem;
  int lh = l >> 4, lh4 = lh * 4;
  int cswz = lh << 4;
#pragma unroll
  for (int n = 0; n < 4; ++n) {
    int col = wn * 64 + n * 16 + lr;
    int colX = col ^ cswz;
    float bv = (z == 0) ? b2e[col] : 0.f;
#pragma unroll
    for (int m = 0; m < 8; ++m) {
      int row = wm * 128 + m * 16 + lh4;
#pragma unroll
      for (int i = 0; i < 4; ++i)
        Cs[(size_t)(row + i) * BT + colX] = f2bf(acc[m][n][i] + bv);
    }
  }
  __syncthreads();
#pragma unroll
  for (int s = 0; s < 16; ++s) {
    int lin = s * 512 + t;
    int row = lin >> 5, c8 = (lin & 31) * 8;
    int c8X = c8 ^ (((row >> 2) & 3) << 4);
    *(ushort8*)(yp + (size_t)(r0 + row) * HDIM + n0 + c8) = *(const ushort8*)(Cs + (size_t)row * BT + c8X);
  }
}

// ---------------- final combine: out[t] = w0*(yA+yB)[s0] + w1*(yA+yB)[s1] ----------------
__global__ void k_reduce(const unsigned short* __restrict__ ypartA,
                         const unsigned short* __restrict__ ypartB,
                         const int2* __restrict__ tok2slot, const float2* __restrict__ ewt,
                         float* __restrict__ out) {
  int idx = blockIdx.x * 256 + threadIdx.x;   // 8 cols per thread
  int t = idx >> 7;
  int c8 = (idx & 127) * 8;
  int2 s = tok2slot[t];
  float2 wv = ewt[t];
  ushort8 a0 = *(const ushort8*)(ypartA + (size_t)s.x * HDIM + c8);
  ushort8 a1 = *(const ushort8*)(ypartB + (size_t)s.x * HDIM + c8);
  ushort8 b0 = *(const ushort8*)(ypartA + (size_t)s.y * HDIM + c8);
  ushort8 b1 = *(const ushort8*)(ypartB + (size_t)s.y * HDIM + c8);
  float o[8];
#pragma unroll
  for (int j = 0; j < 8; ++j)
    o[j] = wv.x * (bf2f((unsigned short)a0[j]) + bf2f((unsigned short)a1[j]))
         + wv.y * (bf2f((unsigned short)b0[j]) + bf2f((unsigned short)b1[j]));
  float* op = out + (size_t)t * HDIM + c8;
  *(float4*)op = make_float4(o[0], o[1], o[2], o[3]);
  *(float4*)(op + 4) = make_float4(o[4], o[5], o[6], o[7]);
}

extern "C" void kernel_launch(void* const* d_in, const int* in_sizes, int n_in,
                              void* d_out, int out_size, void* d_ws, size_t ws_size,
                              hipStream_t stream) {
  const float* x  = (const float*)d_in[0];
  const float* gw = (const float*)d_in[1];
  const float* w1 = (const float*)d_in[2];
  const float* b1 = (const float*)d_in[3];
  const float* w2 = (const float*)d_in[4];
  const float* b2 = (const float*)d_in[5];
  float* out = (float*)d_out;

  char* ws = (char*)d_ws;
  size_t off = 0;
  unsigned short* xb = (unsigned short*)(ws + off); off += (size_t)T_TOK * HDIM * 2;
  int2*   eidx = (int2*)(ws + off);   off += (size_t)T_TOK * 8;
  float2* ewt  = (float2*)(ws + off); off += (size_t)T_TOK * 8;
  int2* tok2slot = (int2*)(ws + off); off += (size_t)T_TOK * 8;
  int*  list_tok = (int*)(ws + off);  off += (size_t)NEXP * T_TOK * 4;
  int* counts  = (int*)(ws + off); off += 64;
  int* off_pad = (int*)(ws + off); off += 64;
  off = (off + 255) & ~(size_t)255;
  unsigned short* h      = (unsigned short*)(ws + off); off += (size_t)RCAP * FDIM * 2;
  unsigned short* wT     = (unsigned short*)(ws + off); off += (size_t)NEXP * HDIM * FDIM * 2;
  unsigned short* ypartA = (unsigned short*)(ws + off); off += (size_t)RCAP * HDIM * 2;
  unsigned short* ypartB = (unsigned short*)(ws + off); off += (size_t)RCAP * HDIM * 2;
  if (ws_size < off) return;  // workspace too small -> fail loudly

  hipFuncSetAttribute((const void*)k_gemm1, hipFuncAttributeMaxDynamicSharedMemorySize, 131072);
  hipFuncSetAttribute((const void*)k_gemm2, hipFuncAttributeMaxDynamicSharedMemorySize, 131072);

  k_gate<<<T_TOK / 4, 256, 0, stream>>>(x, gw, xb, eidx, ewt);
  k_compact<<<NEXP, 1024, 0, stream>>>(eidx, list_tok, counts);
  k_offsets<<<1, 64, 0, stream>>>(counts, off_pad);
  k_invert<<<dim3(T_TOK / 256, NEXP), 256, 0, stream>>>(list_tok, counts, off_pad, eidx, tok2slot);
  // w1 [E][H][F] f32 -> wT [E][F][H] bf16
  k_transp_cvt<<<dim3(FDIM / 64, HDIM / 64, NEXP), 256, 0, stream>>>(w1, wT, HDIM, FDIM);
  k_gemm1<<<8 * 144, 512, 131072, stream>>>(xb, wT, b1, list_tok, counts, off_pad, h);
  // w2 [E][F][H] f32 -> wT [E][H][F] bf16 (buffer reuse after GEMM1)
  k_transp_cvt<<<dim3(HDIM / 64, FDIM / 64, NEXP), 256, 0, stream>>>(w2, wT, FDIM, HDIM);
  k_gemm2<<<8 * 72, 512, 131072, stream>>>(h, wT, b2, off_pad, ypartA, ypartB);
  k_reduce<<<T_TOK * (HDIM / 8) / 256, 256, 0, stream>>>(ypartA, ypartB, tok2slot, ewt, out);
}